// Round 1
// baseline (499.866 us; speedup 1.0000x reference)
//
#include <hip/hip_runtime.h>

// Demosaic BG-Bayer (top-left red) -> RGB, closed-form stencil derived from
// the reference's pad + align_corners bilinear 2x upsample + crop pipeline.
//
// Per output pixel (y,x), H=W=2048:
//   R: (e,e) img[y,x]
//      (e,o) 0.5*(img[y,x-1] + img[y,min(x+1,W-2)])
//      (o,e) 0.5*(img[y-1,x] + img[min(y+1,H-2),x])
//      (o,o) 0.25*sum over {y-1,min(y+1,H-2)} x {x-1,min(x+1,W-2)}
//   B: (o,o) img[y,x]
//      (o,e) 0.5*(img[y,max(x-1,1)] + img[y,x+1])
//      (e,o) 0.5*(img[max(y-1,1),x] + img[y+1,x])
//      (e,e) 0.25*sum over {max(y-1,1),y+1} x {max(x-1,1),x+1}
//   G: green sites ((e,o),(o,e)) identity; else 4-neighbor cross with
//      reflect padding (-1 -> 1, H -> H-2).

#define HH 2048
#define WW 2048

__device__ __forceinline__ float ldx(const float* __restrict__ img, int y, int x) {
    return img[(size_t)y * WW + x];
}

__global__ __launch_bounds__(256) void demosaic_bg_kernel(const float* __restrict__ in,
                                                          float* __restrict__ out) {
    // one thread per 4 horizontal output pixels
    const int strips_per_row = WW / 4;  // 512
    int gid = blockIdx.x * blockDim.x + threadIdx.x;
    int s = gid & (strips_per_row - 1);
    int t = gid >> 9;
    int y = t & (HH - 1);
    int b = t >> 11;
    int x0 = s << 2;

    const float* __restrict__ img = in + (size_t)b * HH * WW;

    float R[4], G[4], B[4];
    const int py = y & 1;

    if (py == 0) {
        // even row: pixels alternate red(e), green(o)
        const int ym = (y == 0) ? 1 : y - 1;       // reflect / max(y-1,1): same for even y
        const int yp = y + 1;                       // <= H-1, no clamp needed on even rows
#pragma unroll
        for (int i = 0; i < 4; ++i) {
            int x = x0 + i;
            if ((x & 1) == 0) {
                // red site
                int xm = (x == 0) ? 1 : x - 1;      // reflect == max(x-1,1) for even x
                int xp = x + 1;                      // <= W-1
                float c  = ldx(img, y, x);
                float u  = ldx(img, ym, x);
                float d  = ldx(img, yp, x);
                float l  = ldx(img, y, xm);
                float r  = ldx(img, y, xp);
                R[i] = c;
                G[i] = 0.25f * (u + d + l + r);
                B[i] = 0.25f * (ldx(img, ym, xm) + ldx(img, ym, xp) +
                                ldx(img, yp, xm) + ldx(img, yp, xp));
            } else {
                // green site (even row, odd col)
                int xc = (x + 1 > WW - 2) ? (WW - 2) : x + 1;  // red clamp right
                R[i] = 0.5f * (ldx(img, y, x - 1) + ldx(img, y, xc));
                G[i] = ldx(img, y, x);
                B[i] = 0.5f * (ldx(img, ym, x) + ldx(img, yp, x));
            }
        }
    } else {
        // odd row: pixels alternate green(e), blue(o)
        const int ycR = (y + 1 > HH - 2) ? (HH - 2) : y + 1;  // red clamp down
        const int ymG = y - 1;                                 // >= 0
        const int ypG = (y == HH - 1) ? (HH - 2) : y + 1;      // reflect down
#pragma unroll
        for (int i = 0; i < 4; ++i) {
            int x = x0 + i;
            if ((x & 1) == 0) {
                // green site (odd row, even col)
                int xm = (x == 0) ? 1 : x - 1;  // blue clamp left: max(x-1,1)
                R[i] = 0.5f * (ldx(img, y - 1, x) + ldx(img, ycR, x));
                G[i] = ldx(img, y, x);
                B[i] = 0.5f * (ldx(img, y, xm) + ldx(img, y, x + 1));
            } else {
                // blue site
                int xcR = (x + 1 > WW - 2) ? (WW - 2) : x + 1;  // red clamp right
                int xpG = (x == WW - 1) ? (WW - 2) : x + 1;     // reflect right
                R[i] = 0.25f * (ldx(img, y - 1, x - 1) + ldx(img, y - 1, xcR) +
                                ldx(img, ycR,  x - 1) + ldx(img, ycR,  xcR));
                G[i] = 0.25f * (ldx(img, ymG, x) + ldx(img, ypG, x) +
                                ldx(img, y, x - 1) + ldx(img, y, xpG));
                B[i] = ldx(img, y, x);
            }
        }
    }

    size_t obase = ((size_t)b * 3) * HH * WW + (size_t)y * WW + x0;
    float4* outR = (float4*)(out + obase);
    float4* outG = (float4*)(out + obase + (size_t)HH * WW);
    float4* outB = (float4*)(out + obase + 2 * (size_t)HH * WW);
    *outR = make_float4(R[0], R[1], R[2], R[3]);
    *outG = make_float4(G[0], G[1], G[2], G[3]);
    *outB = make_float4(B[0], B[1], B[2], B[3]);
}

extern "C" void kernel_launch(void* const* d_in, const int* in_sizes, int n_in,
                              void* d_out, int out_size, void* d_ws, size_t ws_size,
                              hipStream_t stream) {
    const float* in = (const float*)d_in[0];
    float* out = (float*)d_out;
    const int strips = 8 * HH * (WW / 4);           // 8.4M threads
    dim3 block(256);
    dim3 grid(strips / 256);
    demosaic_bg_kernel<<<grid, block, 0, stream>>>(in, out);
}

// Round 2
// 476.407 us; speedup vs baseline: 1.0492x; 1.0492x over previous
//
#include <hip/hip_runtime.h>

// Demosaic BG-Bayer (top-left red) -> RGB, closed-form stencil.
// Each thread computes a 2(row)x4(col) output block, loading 4 input rows:
//   r0 = max(y-1,1), r1 = y, r2 = y+1, r3 = min(y+2,2046)   (y even)
// per row: center float4 [x0..x0+3], left scalar at max(x0-1,1),
//          right scalar at min(x0+4,2046).
// These clamped edge loads are exact for every site case:
//   red-channel right/down clamp  = min(.+1, N-2)
//   blue-channel left/up clamp    = max(.-1, 1)
//   green reflect pad             = -1 -> 1, N -> N-2
// (verified symbolically against the align_corners bilinear upsample ref).

#define HH 2048
#define WW 2048

struct Row { float l; float4 c; float r; };

__device__ __forceinline__ Row load_row(const float* __restrict__ p, int x0) {
    Row o;
    int xl = (x0 == 0) ? 1 : x0 - 1;
    int xr = (x0 + 4 > WW - 2) ? (WW - 2) : x0 + 4;
    o.l = p[xl];
    o.c = *(const float4*)(p + x0);
    o.r = p[xr];
    return o;
}

__global__ __launch_bounds__(256) void demosaic_bg_kernel(const float* __restrict__ in,
                                                          float* __restrict__ out) {
    // thread -> (batch b, even row y, 4-col strip x0)
    const int strips_per_row = WW / 4;  // 512
    int gid = blockIdx.x * blockDim.x + threadIdx.x;
    int s = gid & (strips_per_row - 1);
    int t = gid >> 9;
    int yp = t & (HH / 2 - 1);   // row pair index
    int b = t >> 10;
    int y = yp << 1;             // even
    int x0 = s << 2;

    const float* __restrict__ img = in + (size_t)b * HH * WW;

    const int i0 = (y == 0) ? 1 : y - 1;
    const int i3 = (y + 2 > HH - 2) ? (HH - 2) : y + 2;

    Row r0 = load_row(img + (size_t)i0 * WW, x0);
    Row r1 = load_row(img + (size_t)y * WW, x0);
    Row r2 = load_row(img + (size_t)(y + 1) * WW, x0);
    Row r3 = load_row(img + (size_t)i3 * WW, x0);

    // ---- even output row y: [red, green, red, green] ----
    float4 Re, Ge, Be;
    Re.x = r1.c.x;
    Ge.x = 0.25f * (r0.c.x + r2.c.x + r1.l + r1.c.y);
    Be.x = 0.25f * (r0.l + r0.c.y + r2.l + r2.c.y);

    Re.y = 0.5f * (r1.c.x + r1.c.z);
    Ge.y = r1.c.y;
    Be.y = 0.5f * (r0.c.y + r2.c.y);

    Re.z = r1.c.z;
    Ge.z = 0.25f * (r0.c.z + r2.c.z + r1.c.y + r1.c.w);
    Be.z = 0.25f * (r0.c.y + r0.c.w + r2.c.y + r2.c.w);

    Re.w = 0.5f * (r1.c.z + r1.r);
    Ge.w = r1.c.w;
    Be.w = 0.5f * (r0.c.w + r2.c.w);

    // ---- odd output row y+1: [green, blue, green, blue] ----
    float4 Ro, Go, Bo;
    Ro.x = 0.5f * (r1.c.x + r3.c.x);
    Go.x = r2.c.x;
    Bo.x = 0.5f * (r2.l + r2.c.y);

    Ro.y = 0.25f * (r1.c.x + r1.c.z + r3.c.x + r3.c.z);
    Go.y = 0.25f * (r1.c.y + r3.c.y + r2.c.x + r2.c.z);
    Bo.y = r2.c.y;

    Ro.z = 0.5f * (r1.c.z + r3.c.z);
    Go.z = r2.c.z;
    Bo.z = 0.5f * (r2.c.y + r2.c.w);

    Ro.w = 0.25f * (r1.c.z + r1.r + r3.c.z + r3.r);
    Go.w = 0.25f * (r1.c.w + r3.c.w + r2.c.z + r2.r);
    Bo.w = r2.c.w;

    const size_t plane = (size_t)HH * WW;
    size_t obase = (size_t)b * 3 * plane + (size_t)y * WW + x0;
    *(float4*)(out + obase)                 = Re;
    *(float4*)(out + obase + WW)            = Ro;
    *(float4*)(out + obase + plane)         = Ge;
    *(float4*)(out + obase + plane + WW)    = Go;
    *(float4*)(out + obase + 2 * plane)     = Be;
    *(float4*)(out + obase + 2 * plane + WW) = Bo;
}

extern "C" void kernel_launch(void* const* d_in, const int* in_sizes, int n_in,
                              void* d_out, int out_size, void* d_ws, size_t ws_size,
                              hipStream_t stream) {
    const float* in = (const float*)d_in[0];
    float* out = (float*)d_out;
    const int threads = 8 * (HH / 2) * (WW / 4);   // 4.19M
    dim3 block(256);
    dim3 grid(threads / 256);
    demosaic_bg_kernel<<<grid, block, 0, stream>>>(in, out);
}